// Round 8
// baseline (498.877 us; speedup 1.0000x reference)
//
#include <hip/hip_runtime.h>

#define BATCH 32768
#define NVEC  4096
#define EDIM  256
#define KNN   20

#define BM 64            // samples per block
#define BNC 256          // codebook rows per chunk
#define BKS 32           // K depth per stage
#define NHALF 2048       // rows per block (N split in 2)
#define NTHREADS 256     // 4 waves
#define NCH (NHALF / BNC)    // 8 chunks
#define NST (EDIM / BKS)     // 8 stages
#define CAP 128          // candidate capacity per sample
#define MARGIN 2.0f      // > 2 * worst-case bf16 dot error (~0.6)

typedef short          s16x8 __attribute__((ext_vector_type(8)));
typedef unsigned short u16x8 __attribute__((ext_vector_type(8)));
typedef float          f32x4 __attribute__((ext_vector_type(4)));

__device__ __forceinline__ void gload16(const void* g, void* l) {
  __builtin_amdgcn_global_load_lds(
      (const __attribute__((address_space(1))) unsigned int*)g,
      (__attribute__((address_space(3))) unsigned int*)l,
      16, 0, 0);
}

__device__ __forceinline__ unsigned short f2bf(float f) {
  unsigned int u = __float_as_uint(f);
  u += 0x7fffu + ((u >> 16) & 1u);   // RNE; inputs finite
  return (unsigned short)(u >> 16);
}

// monotone float<->uint encoding: order-preserving over all finite floats
__device__ __forceinline__ unsigned int fenc(float f) {
  unsigned int u = __float_as_uint(f);
  return (u & 0x80000000u) ? ~u : (u | 0x80000000u);
}
__device__ __forceinline__ float fdec(unsigned int e) {
  unsigned int u = (e & 0x80000000u) ? (e ^ 0x80000000u) : ~e;
  return __uint_as_float(u);
}

// fp32 k-ascending dot — EXACT source pattern of round-3's passing kernel
// (same compiler contraction => same rounding class as the np reference).
__device__ __forceinline__ float dot_np(const float4* __restrict__ xq,
                                        const float4* __restrict__ wq) {
  float d = 0.f;
  for (int k = 0; k < EDIM / 4; k++) {
    float4 a4 = xq[k], b4 = wq[k];
    d += a4.x * b4.x;
    d += a4.y * b4.y;
    d += a4.z * b4.z;
    d += a4.w * b4.w;
  }
  return d;
}

__global__ __launch_bounds__(256)
void k_convert_w(const float* __restrict__ W, unsigned short* __restrict__ Wb) {
  int i = blockIdx.x * 256 + threadIdx.x;   // 262144 float4 groups
  float4 v = ((const float4*)W)[i];
  ushort4 o; o.x = f2bf(v.x); o.y = f2bf(v.y); o.z = f2bf(v.z); o.w = f2bf(v.w);
  ((ushort4*)Wb)[i] = o;
}

// dist[n][m] = sum_k W[n][k]*x[m][k].  A = W rows, B = x samples (col=lane&15).
// x fragments live in registers; W double-buffered 16 KB LDS slabs via
// global_load_lds (m97 pattern: barrier -> prefetch next -> consume current).
__global__ __launch_bounds__(NTHREADS, 2)
void k_gemm_argmin(const float* __restrict__ x, const float* __restrict__ W,
                   const unsigned short* __restrict__ Wb,
                   unsigned int* __restrict__ grmin, int* __restrict__ growcnt,
                   int* __restrict__ cidx, float* __restrict__ cval) {
  __shared__ unsigned short wbuf[2][BNC * BKS];   // 2 x 16 KB
  __shared__ unsigned int rowmin_enc[BM];

  const int t    = threadIdx.x;
  const int lane = t & 63;
  const int wv   = t >> 6;       // 0..3: 64-row strip of each 256-chunk
  const int lm   = lane & 15;
  const int lq   = lane >> 4;
  const int m0   = blockIdx.x * BM;
  const int nb0  = blockIdx.y * NHALF;   // this block's first codebook row

  if (t < BM) rowmin_enc[t] = 0xFFFFFFFFu;

  // ---- x fragments: fp32 global -> RNE bf16 -> registers (B-operand layout) ----
  s16x8 xf[NST][4];
  #pragma unroll
  for (int j = 0; j < 4; j++) {
    const float* xp = x + (size_t)(m0 + j * 16 + lm) * EDIM + lq * 8;
    #pragma unroll
    for (int s = 0; s < NST; s++) {
      float4 v0 = *(const float4*)(xp + s * BKS);
      float4 v1 = *(const float4*)(xp + s * BKS + 4);
      u16x8 u;
      u[0] = f2bf(v0.x); u[1] = f2bf(v0.y); u[2] = f2bf(v0.z); u[3] = f2bf(v0.w);
      u[4] = f2bf(v1.x); u[5] = f2bf(v1.y); u[6] = f2bf(v1.z); u[7] = f2bf(v1.w);
      xf[s][j] = __builtin_bit_cast(s16x8, u);
    }
  }

  // stage one (nc, s) W slab: 256 rows x 32 bf16 = 16 KB (4 gload16/thread)
  auto stage_w = [&](int nc, int s, int p) {
    const char* gw = (const char*)Wb + (size_t)(nb0 + nc * BNC) * (EDIM * 2)
                   + s * (BKS * 2);
    int fw = wv * 1024;
    #pragma unroll
    for (int rnd = 0; rnd < 4; rnd++) {
      int f = fw + lane * 16;
      int row = f >> 6, inr = f & 63;   // 64 B per LDS row (32 bf16)
      gload16(gw + (size_t)row * (EDIM * 2) + inr, (char*)wbuf[p] + fw);
      fw += 4096;
    }
  };

  stage_w(0, 0, 0);

  const int abase = (wv * 64 + lm) * BKS + lq * 8;   // W-lds ushort index base
  const f32x4 fz = {0.f, 0.f, 0.f, 0.f};

  for (int nc = 0; nc < NCH; nc++) {
    f32x4 acc[4][4];
    #pragma unroll
    for (int i = 0; i < 4; i++)
      #pragma unroll
      for (int j = 0; j < 4; j++) acc[i][j] = fz;

    #pragma unroll
    for (int s = 0; s < NST; s++) {
      __syncthreads();   // prefetch (this stage) landed; other buf's readers done
      int ns = s + 1, nnc = nc;
      if (ns == NST) { ns = 0; nnc++; }
      if (nnc < NCH) stage_w(nnc, ns, (s + 1) & 1);   // prefetch next slab
      const unsigned short* cw = wbuf[s & 1];
      s16x8 a[4];
      #pragma unroll
      for (int i = 0; i < 4; i++)
        a[i] = *(const s16x8*)(cw + abase + i * (16 * BKS));
      #pragma unroll
      for (int i = 0; i < 4; i++)
        #pragma unroll
        for (int j = 0; j < 4; j++)
          acc[i][j] = __builtin_amdgcn_mfma_f32_16x16x32_bf16(a[i], xf[s][j], acc[i][j], 0, 0, 0);
    }

    const int nbase = nb0 + nc * BNC;

    // ---- per-sample running min (merged across waves, block-local) ----
    #pragma unroll
    for (int j = 0; j < 4; j++) {
      float m = acc[0][j][0];
      #pragma unroll
      for (int i = 0; i < 4; i++)
        #pragma unroll
        for (int r = 0; r < 4; r++) m = fminf(m, acc[i][j][r]);
      m = fminf(m, __shfl_xor(m, 16));
      m = fminf(m, __shfl_xor(m, 32));
      if (lq == 0) atomicMin(&rowmin_enc[j * 16 + lm], fenc(m));
    }
    __syncthreads();

    // ---- layout self-check (last local chunk): one exact dot per thread ----
    if (nc == NCH - 1) {
      int n_chk = nbase + wv * 64 + lq * 4;   // i=0, r=0
      int s_chk = m0 + lm;                    // j=0
      float ex = dot_np((const float4*)(x + (size_t)s_chk * EDIM),
                        (const float4*)(W + (size_t)n_chk * EDIM));
      if (fabsf(ex - acc[0][0][0]) > 2.0f) atomicOr(growcnt + BATCH, 1);
    }

    // ---- candidate capture: threshold = local running min + margin ----
    #pragma unroll
    for (int j = 0; j < 4; j++) {
      int sl = j * 16 + lm;
      float th = fdec(rowmin_enc[sl]) + MARGIN;
      #pragma unroll
      for (int i = 0; i < 4; i++)
        #pragma unroll
        for (int r = 0; r < 4; r++) {
          float v = acc[i][j][r];
          if (v <= th) {
            int n = nbase + wv * 64 + i * 16 + lq * 4 + r;
            int slot = atomicAdd(&growcnt[m0 + sl], 1);
            if (slot < CAP) {
              size_t o = (size_t)(m0 + sl) * CAP + slot;
              cidx[o] = n; cval[o] = v;
            }
          }
        }
    }
  }

  // merge block-local minima into global per-sample min
  if (t < BM) atomicMin(&grmin[m0 + t], rowmin_enc[t]);
}

// fused refine (np-order fp32 argmin over survivors) + weighted-window output.
// one sample per wave.
__global__ __launch_bounds__(256)
void k_refine_out(const float* __restrict__ x, const float* __restrict__ W,
                  const unsigned int* __restrict__ grmin,
                  const int* __restrict__ growcnt,
                  const int* __restrict__ cidx, const float* __restrict__ cval,
                  float* __restrict__ out) {
  const int lane = threadIdx.x & 63;
  const int b = blockIdx.x * 4 + (threadIdx.x >> 6);

  const int bad = growcnt[BATCH];
  int c = growcnt[b];
  bool ovf = (bad != 0) || (c > CAP);
  if (c > CAP) c = CAP;
  const float vfin = fdec(grmin[b]) + MARGIN;
  const float4* xq = (const float4*)(x + (size_t)b * EDIM);

  unsigned long long bestkey = 0xFFFFFFFFFFFFFFFFull;
  if (!ovf) {
    int n = 0; bool act = false;
    if (lane < c) {
      size_t o = (size_t)b * CAP + lane;
      n = cidx[o]; act = (cval[o] <= vfin);
    }
    if (act) {
      float d = dot_np(xq, (const float4*)(W + (size_t)n * EDIM));
      bestkey = ((unsigned long long)fenc(d) << 32) | (unsigned)n;
    }
  } else {
    // fallback (layout-bad or capture overflow): full scan, np-order fp32
    for (int n = lane; n < NVEC; n += 64) {
      float d = dot_np(xq, (const float4*)(W + (size_t)n * EDIM));
      unsigned long long key = ((unsigned long long)fenc(d) << 32) | (unsigned)n;
      if (key < bestkey) bestkey = key;
    }
  }
  #pragma unroll
  for (int off = 32; off >= 1; off >>= 1) {
    unsigned long long o = __shfl_xor(bestkey, off);
    if (o < bestkey) bestkey = o;
  }
  const int ix = (int)(unsigned int)(bestkey & 0xFFFFFFFFull);

  // ---- weighted window output (reference's left-edge quirk included) ----
  float w = 0.f;
  if (lane < 41) {
    int d = lane - KNN;
    int idx = ix + d;
    bool left  = (ix - KNN) < 0;
    bool valid = (idx >= 0) && (idx < NVEC) && (!left || (d < KNN));
    w = valid ? expf(-0.5f * (float)(d * d)) : 0.f;
  }
  float ssum = w;
  #pragma unroll
  for (int off = 32; off >= 1; off >>= 1) ssum += __shfl_xor(ssum, off);
  float inv = 1.f / ssum;

  float4 acc = {0.f, 0.f, 0.f, 0.f};
  #pragma unroll
  for (int d = 0; d < 41; d++) {
    float wd = __shfl(w, d);
    int idx = ix + d - KNN;
    idx = idx < 0 ? 0 : (idx >= NVEC ? NVEC - 1 : idx);
    float4 wr = *(const float4*)(W + (size_t)idx * EDIM + lane * 4);
    acc.x += wd * wr.x; acc.y += wd * wr.y;
    acc.z += wd * wr.z; acc.w += wd * wr.w;
  }
  acc.x *= inv; acc.y *= inv; acc.z *= inv; acc.w *= inv;
  *(float4*)(out + (size_t)b * EDIM + lane * 4) = acc;
}

extern "C" void kernel_launch(void* const* d_in, const int* in_sizes, int n_in,
                              void* d_out, int out_size, void* d_ws, size_t ws_size,
                              hipStream_t stream) {
  const float* x = (const float*)d_in[0];   // [32768,256] fp32
  const float* W = (const float*)d_in[1];   // [4096,256]  fp32
  float* out = (float*)d_out;

  char* ws = (char*)d_ws;
  unsigned short* Wb   = (unsigned short*)ws;                     // 2 MB
  char* p = ws + (size_t)NVEC * EDIM * 2;
  unsigned int* grmin  = (unsigned int*)p;  p += (size_t)BATCH * 4;        // 128 KB
  int*          growcnt= (int*)p;           p += (size_t)(BATCH + 1) * 4;  // 128 KB + badflag
  int*          cidx   = (int*)p;           p += (size_t)BATCH * CAP * 4;  // 16 MB
  float*        cval   = (float*)p;                                        // 16 MB

  hipMemsetAsync(grmin, 0xFF, (size_t)BATCH * 4, stream);
  hipMemsetAsync(growcnt, 0, (size_t)(BATCH + 1) * 4, stream);

  k_convert_w<<<NVEC * EDIM / 4 / 256, 256, 0, stream>>>(W, Wb);
  dim3 grid(BATCH / BM, NVEC / NHALF);   // 512 x 2
  k_gemm_argmin<<<grid, NTHREADS, 0, stream>>>(x, W, Wb, grmin, growcnt, cidx, cval);
  k_refine_out<<<BATCH / 4, 256, 0, stream>>>(x, W, grmin, growcnt, cidx, cval, out);
}

// Round 9
// 418.514 us; speedup vs baseline: 1.1920x; 1.1920x over previous
//
#include <hip/hip_runtime.h>

#define BATCH 32768
#define NVEC  4096
#define EDIM  256
#define KNN   20

#define TM 128           // W rows per tile
#define TN 128           // samples per tile
#define BK 64            // K per stage
#define NST (EDIM / BK)  // 4 stages
#define NTHREADS 256     // 4 waves (2x2)
#define CAP 96           // candidate capacity per sample (E~42)
#define MARGIN 2.0f      // > 2 * worst-case bf16 dot error (~0.5)

typedef short          s16x8 __attribute__((ext_vector_type(8)));
typedef float          f32x4 __attribute__((ext_vector_type(4)));

__device__ __forceinline__ void gload16(const void* g, void* l) {
  __builtin_amdgcn_global_load_lds(
      (const __attribute__((address_space(1))) unsigned int*)g,
      (__attribute__((address_space(3))) unsigned int*)l,
      16, 0, 0);
}

__device__ __forceinline__ unsigned short f2bf(float f) {
  unsigned int u = __float_as_uint(f);
  u += 0x7fffu + ((u >> 16) & 1u);   // RNE; inputs finite
  return (unsigned short)(u >> 16);
}

// monotone float<->uint encoding: order-preserving over all finite floats
__device__ __forceinline__ unsigned int fenc(float f) {
  unsigned int u = __float_as_uint(f);
  return (u & 0x80000000u) ? ~u : (u | 0x80000000u);
}
__device__ __forceinline__ float fdec(unsigned int e) {
  unsigned int u = (e & 0x80000000u) ? (e ^ 0x80000000u) : ~e;
  return __uint_as_float(u);
}

// fp32 k-ascending dot — EXACT source pattern of round-3's passing kernel
// (same compiler contraction => same rounding class as the np reference).
__device__ __forceinline__ float dot_np(const float4* __restrict__ xq,
                                        const float4* __restrict__ wq) {
  float d = 0.f;
  for (int k = 0; k < EDIM / 4; k++) {
    float4 a4 = xq[k], b4 = wq[k];
    d += a4.x * b4.x;
    d += a4.y * b4.y;
    d += a4.z * b4.z;
    d += a4.w * b4.w;
  }
  return d;
}

// convert x and W to bf16 (RNE)
__global__ __launch_bounds__(256)
void k_convert(const float* __restrict__ x, const float* __restrict__ W,
               unsigned short* __restrict__ xb, unsigned short* __restrict__ Wb) {
  const int XG = BATCH * EDIM / 4;   // 2097152
  int i = blockIdx.x * 256 + threadIdx.x;
  if (i < XG) {
    float4 v = ((const float4*)x)[i];
    ushort4 o; o.x = f2bf(v.x); o.y = f2bf(v.y); o.z = f2bf(v.z); o.w = f2bf(v.w);
    ((ushort4*)xb)[i] = o;
  } else {
    int j = i - XG;
    float4 v = ((const float4*)W)[j];
    ushort4 o; o.x = f2bf(v.x); o.y = f2bf(v.y); o.z = f2bf(v.z); o.w = f2bf(v.w);
    ((ushort4*)Wb)[j] = o;
  }
}

// per-code weighted-window output table O[4096][256]
__global__ __launch_bounds__(256)
void k_code_out(const float* __restrict__ W, float* __restrict__ Otab) {
  const int lane = threadIdx.x & 63;
  const int code = blockIdx.x * 4 + (threadIdx.x >> 6);
  float w = 0.f;
  if (lane < 41) {
    int d = lane - KNN;
    int idx = code + d;
    bool left  = (code - KNN) < 0;
    bool valid = (idx >= 0) && (idx < NVEC) && (!left || (d < KNN));
    w = valid ? expf(-0.5f * (float)(d * d)) : 0.f;
  }
  float ssum = w;
  #pragma unroll
  for (int off = 32; off >= 1; off >>= 1) ssum += __shfl_xor(ssum, off);
  float inv = 1.f / ssum;

  float4 acc = {0.f, 0.f, 0.f, 0.f};
  #pragma unroll
  for (int d = 0; d < 41; d++) {
    float wd = __shfl(w, d);
    int idx = code + d - KNN;
    idx = idx < 0 ? 0 : (idx >= NVEC ? NVEC - 1 : idx);
    float4 wr = *(const float4*)(W + (size_t)idx * EDIM + lane * 4);
    acc.x += wd * wr.x; acc.y += wd * wr.y;
    acc.z += wd * wr.z; acc.w += wd * wr.w;
  }
  acc.x *= inv; acc.y *= inv; acc.z *= inv; acc.w *= inv;
  *(float4*)(Otab + (size_t)code * EDIM + lane * 4) = acc;
}

// m97-shape GEMM: D[row][sample], 128x128 tile, K=256 in 4 stages of 64.
// A = W rows, B = x samples; both staged LDS via global_load_lds width=16.
__global__ __launch_bounds__(NTHREADS, 3)
void k_gemm_argmin(const float* __restrict__ x, const float* __restrict__ W,
                   const unsigned short* __restrict__ xb,
                   const unsigned short* __restrict__ Wb,
                   int* __restrict__ growcnt,
                   int* __restrict__ cidx, float* __restrict__ cval) {
  __shared__ unsigned short as[TM * BK];   // 16 KB  [row][k]
  __shared__ unsigned short bs[TN * BK];   // 16 KB  [sample][k]
  __shared__ unsigned int smin[TN];

  const int t    = threadIdx.x;
  const int lane = t & 63;
  const int wv   = t >> 6;
  const int wm   = wv & 1;       // row half
  const int wn   = wv >> 1;      // sample half
  const int lm   = lane & 15;
  const int lq   = lane >> 4;
  const int n0   = blockIdx.x * TN;   // first sample
  const int r0   = blockIdx.y * TM;   // first W row

  if (t < TN) smin[t] = 0xFFFFFFFFu;

  const char* gA = (const char*)(Wb + (size_t)r0 * EDIM);
  const char* gB = (const char*)(xb + (size_t)n0 * EDIM);

  const int ab = (wm * 64 + lm) * BK + lq * 8;   // A-lds ushort base (+ i*16*BK + kk*32)
  const int bb = (wn * 64 + lm) * BK + lq * 8;   // B-lds ushort base (+ j*16*BK + kk*32)
  const f32x4 fz = {0.f, 0.f, 0.f, 0.f};

  f32x4 acc[4][4];
  #pragma unroll
  for (int i = 0; i < 4; i++)
    #pragma unroll
    for (int j = 0; j < 4; j++) acc[i][j] = fz;

  for (int s = 0; s < NST; s++) {
    __syncthreads();   // prior stage's consumers done (and smin init on s=0)
    {
      // stage A & B slabs: 128 rows x 64 bf16 = 16 KB each; 4 rounds x 4 KB
      int fw = wv * 1024;
      #pragma unroll
      for (int rnd = 0; rnd < 4; rnd++) {
        int f = fw + lane * 16;
        int row = f >> 7, inr = f & 127;   // 128 B per slab row
        size_t goff = (size_t)row * (EDIM * 2) + s * (BK * 2) + inr;
        gload16(gA + goff, (char*)as + fw);
        gload16(gB + goff, (char*)bs + fw);
        fw += 4096;
      }
    }
    __syncthreads();   // barrier drains vmcnt -> slabs visible
    #pragma unroll
    for (int kk = 0; kk < 2; kk++) {
      s16x8 a[4], b[4];
      #pragma unroll
      for (int i = 0; i < 4; i++)
        a[i] = *(const s16x8*)(as + ab + i * (16 * BK) + kk * 32);
      #pragma unroll
      for (int j = 0; j < 4; j++)
        b[j] = *(const s16x8*)(bs + bb + j * (16 * BK) + kk * 32);
      #pragma unroll
      for (int i = 0; i < 4; i++)
        #pragma unroll
        for (int j = 0; j < 4; j++)
          acc[i][j] = __builtin_amdgcn_mfma_f32_16x16x32_bf16(a[i], b[j], acc[i][j], 0, 0, 0);
    }
  }

  // ---- per-sample block-local min over the 128 rows ----
  #pragma unroll
  for (int j = 0; j < 4; j++) {
    float m = acc[0][j][0];
    #pragma unroll
    for (int i = 0; i < 4; i++)
      #pragma unroll
      for (int r = 0; r < 4; r++) m = fminf(m, acc[i][j][r]);
    m = fminf(m, __shfl_xor(m, 16));
    m = fminf(m, __shfl_xor(m, 32));
    if (lq == 0) atomicMin(&smin[wn * 64 + j * 16 + lm], fenc(m));
  }
  __syncthreads();

  // ---- layout self-check (block 0 only): exact dot vs acc[0][0][0] ----
  if (blockIdx.x == 0 && blockIdx.y == 0) {
    int n_chk = r0 + wm * 64 + lq * 4;        // i=0, r=0 row
    int s_chk = n0 + wn * 64 + lm;            // j=0 sample
    float ex = dot_np((const float4*)(x + (size_t)s_chk * EDIM),
                      (const float4*)(W + (size_t)n_chk * EDIM));
    if (fabsf(ex - acc[0][0][0]) > 2.0f) atomicOr(growcnt + BATCH, 1);
  }

  // ---- candidate capture vs local min + margin ----
  #pragma unroll
  for (int j = 0; j < 4; j++) {
    int col = wn * 64 + j * 16 + lm;
    float th = fdec(smin[col]) + MARGIN;
    #pragma unroll
    for (int i = 0; i < 4; i++)
      #pragma unroll
      for (int r = 0; r < 4; r++) {
        float v = acc[i][j][r];
        if (v <= th) {
          int n = r0 + wm * 64 + i * 16 + lq * 4 + r;
          int slot = atomicAdd(&growcnt[n0 + col], 1);
          if (slot < CAP) {
            size_t o = (size_t)(n0 + col) * CAP + slot;
            cidx[o] = n; cval[o] = v;
          }
        }
      }
  }
}

// refine: one wave per sample. global min is provably among captures, so the
// filter threshold is min(cval)+MARGIN. np-order fp32 dots, tie -> smaller idx.
__global__ __launch_bounds__(256)
void k_refine(const float* __restrict__ x, const float* __restrict__ W,
              const int* __restrict__ growcnt,
              const int* __restrict__ cidx, const float* __restrict__ cval,
              int* __restrict__ ixo) {
  const int lane = threadIdx.x & 63;
  const int b = blockIdx.x * 4 + (threadIdx.x >> 6);

  const int bad = growcnt[BATCH];
  int c = growcnt[b];
  bool ovf = (bad != 0) || (c > CAP);
  if (c > CAP) c = CAP;
  const float4* xq = (const float4*)(x + (size_t)b * EDIM);

  unsigned long long bestkey = 0xFFFFFFFFFFFFFFFFull;
  if (!ovf) {
    float cv[2]; int cn[2];
    #pragma unroll
    for (int u = 0; u < 2; u++) {
      int sidx = lane + u * 64;
      cv[u] = 3.4e38f; cn[u] = 0;
      if (sidx < c) {
        size_t o = (size_t)b * CAP + sidx;
        cv[u] = cval[o]; cn[u] = cidx[o];
      }
    }
    float vmin = fminf(cv[0], cv[1]);
    #pragma unroll
    for (int off = 32; off >= 1; off >>= 1) vmin = fminf(vmin, __shfl_xor(vmin, off));
    float th = vmin + MARGIN;
    #pragma unroll
    for (int u = 0; u < 2; u++) {
      if (cv[u] <= th) {
        float d = dot_np(xq, (const float4*)(W + (size_t)cn[u] * EDIM));
        unsigned long long key =
            ((unsigned long long)fenc(d) << 32) | (unsigned)cn[u];
        if (key < bestkey) bestkey = key;
      }
    }
  } else {
    // fallback (layout-bad or capture overflow): full scan, np-order fp32
    for (int n = lane; n < NVEC; n += 64) {
      float d = dot_np(xq, (const float4*)(W + (size_t)n * EDIM));
      unsigned long long key = ((unsigned long long)fenc(d) << 32) | (unsigned)n;
      if (key < bestkey) bestkey = key;
    }
  }
  #pragma unroll
  for (int off = 32; off >= 1; off >>= 1) {
    unsigned long long o = __shfl_xor(bestkey, off);
    if (o < bestkey) bestkey = o;
  }
  if (lane == 0) ixo[b] = (int)(unsigned int)(bestkey & 0xFFFFFFFFull);
}

// out[b] = Otab[ixo[b]]
__global__ __launch_bounds__(256)
void k_scatter(const float* __restrict__ Otab, const int* __restrict__ ixo,
               float* __restrict__ out) {
  const int lane = threadIdx.x & 63;
  const int b = blockIdx.x * 4 + (threadIdx.x >> 6);
  int ix = ixo[b];
  float4 v = *(const float4*)(Otab + (size_t)ix * EDIM + lane * 4);
  *(float4*)(out + (size_t)b * EDIM + lane * 4) = v;
}

extern "C" void kernel_launch(void* const* d_in, const int* in_sizes, int n_in,
                              void* d_out, int out_size, void* d_ws, size_t ws_size,
                              hipStream_t stream) {
  const float* x = (const float*)d_in[0];   // [32768,256] fp32
  const float* W = (const float*)d_in[1];   // [4096,256]  fp32
  float* out = (float*)d_out;

  char* ws = (char*)d_ws;
  unsigned short* xb  = (unsigned short*)ws;                               // 16 MB
  unsigned short* Wb  = (unsigned short*)(ws + (size_t)BATCH * EDIM * 2);  // 2 MB
  char* p = ws + (size_t)(BATCH + NVEC) * EDIM * 2;
  int*   growcnt = (int*)p;   p += (size_t)(BATCH + 1) * 4;                // 128 KB + badflag
  int*   ixo     = (int*)p;   p += (size_t)BATCH * 4;                      // 128 KB
  int*   cidx    = (int*)p;   p += (size_t)BATCH * CAP * 4;                // 12 MB
  float* cval    = (float*)p; p += (size_t)BATCH * CAP * 4;                // 12 MB
  float* Otab    = (float*)p;                                              // 4 MB

  hipMemsetAsync(growcnt, 0, (size_t)(BATCH + 1) * 4, stream);

  k_convert<<<(BATCH + NVEC) * EDIM / 4 / 256, 256, 0, stream>>>(x, W, xb, Wb);
  k_code_out<<<NVEC / 4, 256, 0, stream>>>(W, Otab);
  dim3 grid(BATCH / TN, NVEC / TM);   // 256 x 32
  k_gemm_argmin<<<grid, NTHREADS, 0, stream>>>(x, W, xb, Wb, growcnt, cidx, cval);
  k_refine<<<BATCH / 4, 256, 0, stream>>>(x, W, growcnt, cidx, cval, ixo);
  k_scatter<<<BATCH / 4, 256, 0, stream>>>(Otab, ixo, out);
}

// Round 10
// 384.402 us; speedup vs baseline: 1.2978x; 1.0887x over previous
//
#include <hip/hip_runtime.h>

#define BATCH 32768
#define NVEC  4096
#define EDIM  256
#define KNN   20

#define BM 64            // samples per block
#define NTHREADS 256     // 4 waves
#define RPW 1024         // rows scanned per wave (4 waves x 1024 = all 4096)
#define NCHUNK 16        // RPW / 64
#define XPITCH 264       // x-LDS row pitch in ushorts (256+8: b128 reads conflict-free)
#define CAP 32           // block-local candidate capacity per sample (E~10-14)
#define MARGIN 2.0f      // > 2 * worst-case bf16 dot error (~0.7)

typedef short          s16x8 __attribute__((ext_vector_type(8)));
typedef unsigned short u16x8 __attribute__((ext_vector_type(8)));
typedef float          f32x4 __attribute__((ext_vector_type(4)));

__device__ __forceinline__ unsigned short f2bf(float f) {
  unsigned int u = __float_as_uint(f);
  u += 0x7fffu + ((u >> 16) & 1u);   // RNE; inputs finite
  return (unsigned short)(u >> 16);
}

// monotone float<->uint encoding: order-preserving over all finite floats
__device__ __forceinline__ unsigned int fenc(float f) {
  unsigned int u = __float_as_uint(f);
  return (u & 0x80000000u) ? ~u : (u | 0x80000000u);
}
__device__ __forceinline__ float fdec(unsigned int e) {
  unsigned int u = (e & 0x80000000u) ? (e ^ 0x80000000u) : ~e;
  return __uint_as_float(u);
}

// fp32 k-ascending dot — EXACT source pattern of round-3's passing kernel
// (same compiler contraction => same rounding class as the np reference).
__device__ __forceinline__ float dot_np(const float4* __restrict__ xq,
                                        const float4* __restrict__ wq) {
  float d = 0.f;
  for (int k = 0; k < EDIM / 4; k++) {
    float4 a4 = xq[k], b4 = wq[k];
    d += a4.x * b4.x;
    d += a4.y * b4.y;
    d += a4.z * b4.z;
    d += a4.w * b4.w;
  }
  return d;
}

__global__ __launch_bounds__(256)
void k_convert_w(const float* __restrict__ W, unsigned short* __restrict__ Wb) {
  int i = blockIdx.x * 256 + threadIdx.x;   // 262144 float4 groups
  float4 v = ((const float4*)W)[i];
  ushort4 o; o.x = f2bf(v.x); o.y = f2bf(v.y); o.z = f2bf(v.z); o.w = f2bf(v.w);
  ((ushort4*)Wb)[i] = o;
}

// per-code weighted-window output table O[4096][256]
__global__ __launch_bounds__(256)
void k_code_out(const float* __restrict__ W, float* __restrict__ Otab) {
  const int lane = threadIdx.x & 63;
  const int code = blockIdx.x * 4 + (threadIdx.x >> 6);
  float w = 0.f;
  if (lane < 41) {
    int d = lane - KNN;
    int idx = code + d;
    bool left  = (code - KNN) < 0;
    bool valid = (idx >= 0) && (idx < NVEC) && (!left || (d < KNN));
    w = valid ? expf(-0.5f * (float)(d * d)) : 0.f;
  }
  float ssum = w;
  #pragma unroll
  for (int off = 32; off >= 1; off >>= 1) ssum += __shfl_xor(ssum, off);
  float inv = 1.f / ssum;

  float4 acc = {0.f, 0.f, 0.f, 0.f};
  #pragma unroll
  for (int d = 0; d < 41; d++) {
    float wd = __shfl(w, d);
    int idx = code + d - KNN;
    idx = idx < 0 ? 0 : (idx >= NVEC ? NVEC - 1 : idx);
    float4 wr = *(const float4*)(W + (size_t)idx * EDIM + lane * 4);
    acc.x += wd * wr.x; acc.y += wd * wr.y;
    acc.z += wd * wr.z; acc.w += wd * wr.w;
  }
  acc.x *= inv; acc.y *= inv; acc.z *= inv; acc.w *= inv;
  *(float4*)(Otab + (size_t)code * EDIM + lane * 4) = acc;
}

// fused GEMM + argmin + refine. One block per 64 samples; block scans all
// 4096 rows (wave wv owns rows wv*1024..+1023). No barriers in the row loop:
// x tile in padded LDS, W streamed L2->registers, candidates in LDS.
__global__ __launch_bounds__(NTHREADS, 3)
void k_all(const float* __restrict__ x, const float* __restrict__ W,
           const unsigned short* __restrict__ Wb, int* __restrict__ ixo) {
  __shared__ unsigned short xs[BM * XPITCH];   // 33792 B
  __shared__ float        sval[BM * CAP];      // 8192 B
  __shared__ int          sidx[BM * CAP];      // 8192 B
  __shared__ int          scnt[BM];            // 256 B
  __shared__ unsigned int smin[BM];            // 256 B
  __shared__ int          sbad;

  const int t    = threadIdx.x;
  const int lane = t & 63;
  const int wv   = t >> 6;
  const int lm   = lane & 15;
  const int lq   = lane >> 4;
  const int m0   = blockIdx.x * BM;

  if (t < BM) { scnt[t] = 0; smin[t] = 0xFFFFFFFFu; }
  if (t == 0) sbad = 0;

  // ---- stage x tile: fp32 global -> RNE bf16 -> padded LDS ----
  {
    const int r = t >> 2, q = t & 3;
    const float* xp = x + (size_t)(m0 + r) * EDIM + q * 64;
    unsigned short* dst = xs + r * XPITCH + q * 64;
    #pragma unroll
    for (int u = 0; u < 8; u++) {
      float4 v0 = *(const float4*)(xp + u * 8);
      float4 v1 = *(const float4*)(xp + u * 8 + 4);
      u16x8 uu;
      uu[0] = f2bf(v0.x); uu[1] = f2bf(v0.y); uu[2] = f2bf(v0.z); uu[3] = f2bf(v0.w);
      uu[4] = f2bf(v1.x); uu[5] = f2bf(v1.y); uu[6] = f2bf(v1.z); uu[7] = f2bf(v1.w);
      *(u16x8*)(dst + u * 8) = uu;
    }
  }
  __syncthreads();   // the only pre-refine barrier

  const f32x4 fz = {0.f, 0.f, 0.f, 0.f};
  float rm[4] = {3.4e38f, 3.4e38f, 3.4e38f, 3.4e38f};   // per-lane running min (per j)

  for (int nc = 0; nc < NCHUNK; nc++) {
    const int rb = wv * RPW + nc * 64;
    f32x4 acc[4][4];
    #pragma unroll
    for (int i = 0; i < 4; i++)
      #pragma unroll
      for (int j = 0; j < 4; j++) acc[i][j] = fz;

    const unsigned short* wp = Wb + (size_t)(rb + lm) * EDIM + lq * 8;
    #pragma unroll
    for (int s = 0; s < 8; s++) {
      s16x8 a[4], b[4];
      #pragma unroll
      for (int i = 0; i < 4; i++)
        a[i] = *(const s16x8*)(wp + (size_t)i * (16 * EDIM) + s * 32);
      #pragma unroll
      for (int j = 0; j < 4; j++)
        b[j] = *(const s16x8*)(xs + (j * 16 + lm) * XPITCH + s * 32 + lq * 8);
      #pragma unroll
      for (int i = 0; i < 4; i++)
        #pragma unroll
        for (int j = 0; j < 4; j++)
          acc[i][j] = __builtin_amdgcn_mfma_f32_16x16x32_bf16(a[i], b[j], acc[i][j], 0, 0, 0);
    }

    // ---- per-sample chunk min -> running min (cross-wave shared, no barrier) ----
    #pragma unroll
    for (int j = 0; j < 4; j++) {
      float m = acc[0][j][0];
      #pragma unroll
      for (int i = 0; i < 4; i++)
        #pragma unroll
        for (int r = 0; r < 4; r++) m = fminf(m, acc[i][j][r]);
      m = fminf(m, __shfl_xor(m, 16));
      m = fminf(m, __shfl_xor(m, 32));   // all 4 lq lanes of this lm have sample min
      rm[j] = fminf(rm[j], m);
      unsigned int cur = 0xFFFFFFFFu;
      if (lq == 0) {
        unsigned int old = atomicMin(&smin[j * 16 + lm], fenc(rm[j]));
        cur = old < fenc(rm[j]) ? old : fenc(rm[j]);
      }
      float sh = fdec(__shfl(cur, lm));   // broadcast from the lq==0 lane of this lm
      rm[j] = fminf(rm[j], sh);
    }

    // ---- layout self-check (chunk 0): exact dot vs acc[0][0][0] ----
    if (nc == 0) {
      float ex = dot_np((const float4*)(x + (size_t)(m0 + lm) * EDIM),
                        (const float4*)(W + (size_t)(wv * RPW + lq * 4) * EDIM));
      if (fabsf(ex - acc[0][0][0]) > 2.0f) sbad = 1;
    }

    // ---- candidate capture into LDS vs running min + margin ----
    #pragma unroll
    for (int j = 0; j < 4; j++) {
      int sl = j * 16 + lm;
      float th = rm[j] + MARGIN;
      #pragma unroll
      for (int i = 0; i < 4; i++)
        #pragma unroll
        for (int r = 0; r < 4; r++) {
          float v = acc[i][j][r];
          if (v <= th) {
            int row = rb + i * 16 + lq * 4 + r;
            int slot = atomicAdd(&scnt[sl], 1);
            if (slot < CAP) { sval[sl * CAP + slot] = v; sidx[sl * CAP + slot] = row; }
          }
        }
    }
  }

  __syncthreads();   // all captures visible

  // ---- in-block refine: np-order fp32 dots; min value, tie -> smaller idx ----
  const bool bad = (sbad != 0);
  for (int u = 0; u < 16; u++) {
    const int sl = wv * 16 + u;
    const int b = m0 + sl;
    int c = scnt[sl];
    bool ovf = bad || (c > CAP);
    if (c > CAP) c = CAP;
    const float4* xq = (const float4*)(x + (size_t)b * EDIM);
    unsigned long long bestkey = 0xFFFFFFFFFFFFFFFFull;
    if (!ovf) {
      float v = 3.4e38f; int id = 0;
      if (lane < c) { v = sval[sl * CAP + lane]; id = sidx[sl * CAP + lane]; }
      float vmin = v;
      #pragma unroll
      for (int off = 32; off >= 1; off >>= 1) vmin = fminf(vmin, __shfl_xor(vmin, off));
      if (lane < c && v <= vmin + MARGIN) {
        float d = dot_np(xq, (const float4*)(W + (size_t)id * EDIM));
        bestkey = ((unsigned long long)fenc(d) << 32) | (unsigned)id;
      }
    } else {
      // fallback (layout-bad or capture overflow): full scan, np-order fp32
      for (int n = lane; n < NVEC; n += 64) {
        float d = dot_np(xq, (const float4*)(W + (size_t)n * EDIM));
        unsigned long long key = ((unsigned long long)fenc(d) << 32) | (unsigned)n;
        if (key < bestkey) bestkey = key;
      }
    }
    #pragma unroll
    for (int off = 32; off >= 1; off >>= 1) {
      unsigned long long o = __shfl_xor(bestkey, off);
      if (o < bestkey) bestkey = o;
    }
    if (lane == 0) ixo[b] = (int)(unsigned int)(bestkey & 0xFFFFFFFFull);
  }
}

// out[b] = Otab[ixo[b]]
__global__ __launch_bounds__(256)
void k_scatter(const float* __restrict__ Otab, const int* __restrict__ ixo,
               float* __restrict__ out) {
  const int lane = threadIdx.x & 63;
  const int b = blockIdx.x * 4 + (threadIdx.x >> 6);
  int ix = ixo[b];
  float4 v = *(const float4*)(Otab + (size_t)ix * EDIM + lane * 4);
  *(float4*)(out + (size_t)b * EDIM + lane * 4) = v;
}

extern "C" void kernel_launch(void* const* d_in, const int* in_sizes, int n_in,
                              void* d_out, int out_size, void* d_ws, size_t ws_size,
                              hipStream_t stream) {
  const float* x = (const float*)d_in[0];   // [32768,256] fp32
  const float* W = (const float*)d_in[1];   // [4096,256]  fp32
  float* out = (float*)d_out;

  char* ws = (char*)d_ws;
  unsigned short* Wb = (unsigned short*)ws;                        // 2 MB
  char* p = ws + (size_t)NVEC * EDIM * 2;
  int*   ixo  = (int*)p;   p += (size_t)BATCH * 4;                 // 128 KB
  float* Otab = (float*)p;                                         // 4 MB

  k_convert_w<<<NVEC * EDIM / 4 / 256, 256, 0, stream>>>(W, Wb);
  k_code_out<<<NVEC / 4, 256, 0, stream>>>(W, Otab);
  k_all<<<BATCH / BM, NTHREADS, 0, stream>>>(x, W, Wb, ixo);
  k_scatter<<<BATCH / 4, 256, 0, stream>>>(Otab, ixo, out);
}